// Round 1
// baseline (9163.603 us; speedup 1.0000x reference)
//
#include <hip/hip_runtime.h>
#include <hip/hip_bf16.h>

// GRU sequence: B=64, T=512, LATENT=512, HIDDEN=1024.
// K0: weights fp32->bf16.  K1: x_proj GEMM, output stored t-major.
// K2: ONE persistent kernel runs all 512 timesteps with a per-batch-group
//     device-scope barrier; W_hh lives in VGPRs; fp32 h lives in registers.

#define B_   64
#define T_   512
#define LAT_ 512
#define HID_ 1024
#define G3_  3072

typedef __bf16  bf8  __attribute__((ext_vector_type(8)));
typedef float   f4   __attribute__((ext_vector_type(4)));
typedef short   s8v  __attribute__((ext_vector_type(8)));
typedef short   s4v  __attribute__((ext_vector_type(4)));

__device__ __forceinline__ bf8 ldb8(const short* p) {
    s8v v = *(const s8v*)p;
    return __builtin_bit_cast(bf8, v);
}
__device__ __forceinline__ float b2f(short s) {
    return __bfloat162float(*(__hip_bfloat16*)&s);
}
__device__ __forceinline__ short f2b(float f) {
    __hip_bfloat16 h = __float2bfloat16(f);
    return *(short*)&h;
}

// ---------------------------------------------------------------------------
// K0: fp32 -> bf16 elementwise
// ---------------------------------------------------------------------------
__global__ __launch_bounds__(256) void cvt_f2b_kernel(
    const float* __restrict__ in, short* __restrict__ out, int n)
{
    int i = (blockIdx.x * 256 + threadIdx.x) * 4;
    if (i + 3 < n) {
        f4 v = *(const f4*)(in + i);
        s4v r;
        r.x = f2b(v.x); r.y = f2b(v.y); r.z = f2b(v.z); r.w = f2b(v.w);
        *(s4v*)(out + i) = r;
    }
}

// ---------------------------------------------------------------------------
// K1: XPt[(t*64+b), g] = sum_k Z[b*T+t, k]*Wih[g,k] + bih[g]   (t-major store)
// 128x128 tile, BK=32, 256 threads (2x2 waves of 64x64), mfma 16x16x32 bf16.
// ---------------------------------------------------------------------------
__global__ __launch_bounds__(256) void xproj_kernel(
    const float* __restrict__ Z,     // (32768, 512) fp32, row = b*T + t
    const short* __restrict__ Wih,   // (3072, 512) bf16
    const float* __restrict__ bih,   // (3072) fp32
    short* __restrict__ XP)          // (32768, 3072) bf16, row = t*B + b
{
    __shared__ short As[128 * 32];
    __shared__ short Bs[128 * 32];

    const int tid  = threadIdx.x;
    const int lane = tid & 63;
    const int wid  = tid >> 6;
    const int wm   = wid & 1;
    const int wn   = wid >> 1;
    const int lrow = lane & 15;
    const int quad = lane >> 4;

    const long arow0 = (long)blockIdx.y * 128;   // M tile base
    const long brow0 = (long)blockIdx.x * 128;   // N tile base

    f4 acc[4][4];
    const f4 zf = {0.f, 0.f, 0.f, 0.f};
#pragma unroll
    for (int i = 0; i < 4; i++)
#pragma unroll
        for (int jj = 0; jj < 4; jj++) acc[i][jj] = zf;

    for (int k0 = 0; k0 < LAT_; k0 += 32) {
#pragma unroll
        for (int i = 0; i < 4; i++) {
            int c   = tid + 256 * i;
            int row = c >> 3;
            int kc  = (c & 7) * 4;
            f4 v = *(const f4*)(Z + (arow0 + row) * LAT_ + k0 + kc);
            s4v r;
            r.x = f2b(v.x); r.y = f2b(v.y); r.z = f2b(v.z); r.w = f2b(v.w);
            *(s4v*)(As + row * 32 + kc) = r;
        }
#pragma unroll
        for (int i = 0; i < 2; i++) {
            int c   = tid + 256 * i;
            int row = c >> 2;
            int kc  = (c & 3) * 8;
            *(s8v*)(Bs + row * 32 + kc) = *(const s8v*)(Wih + (brow0 + row) * LAT_ + k0 + kc);
        }
        __syncthreads();

        bf8 af[4], bfr[4];
#pragma unroll
        for (int mf = 0; mf < 4; mf++)
            af[mf] = ldb8(As + (wm * 64 + mf * 16 + lrow) * 32 + quad * 8);
#pragma unroll
        for (int nf = 0; nf < 4; nf++)
            bfr[nf] = ldb8(Bs + (wn * 64 + nf * 16 + lrow) * 32 + quad * 8);

#pragma unroll
        for (int mf = 0; mf < 4; mf++)
#pragma unroll
            for (int nf = 0; nf < 4; nf++)
                acc[mf][nf] = __builtin_amdgcn_mfma_f32_16x16x32_bf16(
                    af[mf], bfr[nf], acc[mf][nf], 0, 0, 0);
        __syncthreads();
    }

    // epilogue: C/D layout col = lane&15, row = quad*4 + reg. Transposed store.
#pragma unroll
    for (int nf = 0; nf < 4; nf++) {
        int gc = (int)brow0 + wn * 64 + nf * 16 + lrow;
        float bias = bih[gc];
#pragma unroll
        for (int mf = 0; mf < 4; mf++) {
#pragma unroll
            for (int r = 0; r < 4; r++) {
                long gr = arow0 + wm * 64 + mf * 16 + quad * 4 + r;   // b*T + t
                long tr = (gr & (T_ - 1)) * B_ + (gr >> 9);            // t*B + b
                XP[tr * G3_ + gc] = f2b(acc[mf][nf][r] + bias);
            }
        }
    }
}

// ---------------------------------------------------------------------------
// barrier slot init (must be zero at persistent-kernel start; re-run per launch)
// ---------------------------------------------------------------------------
__global__ void init_slots(int* slots) { slots[threadIdx.x] = 0; }

// ---------------------------------------------------------------------------
// per-batch-group grid barrier: 64 participants, flat slot array.
// release fence (wbl2) -> signal; wave0 polls 64 slots; acquire fence (inv).
// ---------------------------------------------------------------------------
__device__ __forceinline__ void gbar(int* gslots, int cb, int tid, int lane, int epoch)
{
    __syncthreads();                               // all waves' stores drained
    if (tid == 0) {
        __builtin_amdgcn_fence(__ATOMIC_RELEASE, "agent");   // flush to LLC
        __hip_atomic_store(gslots + cb, epoch,
                           __ATOMIC_RELAXED, __HIP_MEMORY_SCOPE_AGENT);
    }
    if (tid < 64) {                                // wave 0: one slot per lane
        while (__hip_atomic_load(gslots + lane,
                                 __ATOMIC_RELAXED, __HIP_MEMORY_SCOPE_AGENT) < epoch)
            __builtin_amdgcn_s_sleep(1);
    }
    __syncthreads();
    __builtin_amdgcn_fence(__ATOMIC_ACQUIRE, "agent");       // invalidate L1/L2
}

// ---------------------------------------------------------------------------
// K2: persistent GRU recurrence. Grid = 256 blocks x 256 threads.
//   block = (grp = bid>>6: batch rows [grp*16,+16), cb = bid&63: h-cols [cb*16,+16))
//   wave w reduces K-slice [w*256,+256); W_hh slice pinned in 96 VGPRs/wave.
//   fp32 h: 1 register/thread. bf16 h shadow: global, double-buffered.
//   One device-scope barrier per step, per batch-group (groups independent).
// ---------------------------------------------------------------------------
__global__ __launch_bounds__(256, 2) void gru_persist(
    const short* __restrict__ Whh,   // (3072,1024) bf16
    const short* __restrict__ XPt,   // (T*B,3072) bf16, row = t*64+b
    const float* __restrict__ bhh,   // (3072) fp32
    short* __restrict__ Hb0,         // (64,1024) bf16
    short* __restrict__ Hb1,         // (64,1024) bf16
    float* __restrict__ Out,         // (64,512,1024) fp32
    int*  __restrict__ slots)        // (256) pre-zeroed
{
    __shared__ float red[64 * 50];   // [w*16 + mloc][50] padded (12.8 KB)

    const int tid  = threadIdx.x;
    const int lane = tid & 63;
    const int w    = tid >> 6;
    const int lrow = lane & 15;
    const int quad = lane >> 4;
    const int bid  = blockIdx.x;
    const int grp  = bid >> 6;
    const int cb   = bid & 63;
    const int c0   = cb * 16;
    const int m0   = grp * 16;
    const int kbase = w * 256;
    int* gslots = slots + grp * 64;

    // W_hh B-fragments resident in registers: 3 gates x 8 k-chunks x 16 B
    bf8 bfr[3][8];
#pragma unroll
    for (int g = 0; g < 3; g++)
#pragma unroll
        for (int kk = 0; kk < 8; kk++)
            bfr[g][kk] = ldb8(Whh + (g * HID_ + c0 + lrow) * HID_
                                  + kbase + kk * 32 + quad * 8);

    // per-thread gate element: (mloc = tid>>4, j = tid&15)
    const int mloc = tid >> 4;
    const int j    = tid & 15;
    const int mg   = m0 + mloc;                    // global batch row
    const float br = bhh[c0 + j];
    const float bz = bhh[HID_ + c0 + j];
    const float bn = bhh[2 * HID_ + c0 + j];
    float hfp = 0.f;                               // fp32 h, never leaves regs

    // zero own h0 slice (each (row,col) covered exactly once grid-wide)
    Hb0[mg * HID_ + c0 + j] = 0;

    // prefetch x-proj for t=0
    const long tstride = (long)B_ * G3_;
    const short* xpb = XPt + (long)mg * G3_ + c0 + j;
    short xr_s = xpb[0], xz_s = xpb[HID_], xn_s = xpb[2 * HID_];

    gbar(gslots, cb, tid, lane, 1);                // h0 visible group-wide

#pragma unroll 1
    for (int t = 0; t < T_; t++) {
        const short* Hc = (t & 1) ? Hb1 : Hb0;
        short*       Hn = (t & 1) ? Hb0 : Hb1;

        f4 acc[3];
        const f4 zf = {0.f, 0.f, 0.f, 0.f};
        acc[0] = zf; acc[1] = zf; acc[2] = zf;

#pragma unroll
        for (int kk = 0; kk < 8; kk++) {
            bf8 a = ldb8(Hc + (m0 + lrow) * HID_ + kbase + kk * 32 + quad * 8);
#pragma unroll
            for (int g = 0; g < 3; g++)
                acc[g] = __builtin_amdgcn_mfma_f32_16x16x32_bf16(
                    a, bfr[g][kk], acc[g], 0, 0, 0);
        }

        // wave partials -> LDS. m = quad*4 + r, col = g*16 + lrow
#pragma unroll
        for (int g = 0; g < 3; g++)
#pragma unroll
            for (int r = 0; r < 4; r++)
                red[(w * 16 + quad * 4 + r) * 50 + g * 16 + lrow] = acc[g][r];
        __syncthreads();

        // cross-wave reduce + gates (1 element/thread)
        float ghr = 0.f, ghz = 0.f, ghn = 0.f;
#pragma unroll
        for (int ww = 0; ww < 4; ww++) {
            const float* rr = red + (ww * 16 + mloc) * 50 + j;
            ghr += rr[0];
            ghz += rr[16];
            ghn += rr[32];
        }

        float rg = 1.f / (1.f + __expf(-(b2f(xr_s) + ghr + br)));
        float ug = 1.f / (1.f + __expf(-(b2f(xz_s) + ghz + bz)));
        float ng = tanhf(b2f(xn_s) + rg * (ghn + bn));
        float hnew = (1.f - ug) * ng + ug * hfp;
        hfp = hnew;

        Hn[mg * HID_ + c0 + j] = f2b(hnew);
        Out[((long)mg * T_ + t) * HID_ + c0 + j] = hnew;

        if (t + 1 < T_) {
            // prefetch next step's x-proj; latency hides under barrier skew
            const short* xp = xpb + (long)(t + 1) * tstride;
            xr_s = xp[0]; xz_s = xp[HID_]; xn_s = xp[2 * HID_];
            gbar(gslots, cb, tid, lane, t + 2);
        }
    }
}

extern "C" void kernel_launch(void* const* d_in, const int* in_sizes, int n_in,
                              void* d_out, int out_size, void* d_ws, size_t ws_size,
                              hipStream_t stream) {
    const float* Z   = (const float*)d_in[0];   // (64,512,512)
    const float* Wih = (const float*)d_in[1];   // (3072,512)
    const float* Whh = (const float*)d_in[2];   // (3072,1024)
    const float* bih = (const float*)d_in[3];   // (3072)
    const float* bhh = (const float*)d_in[4];   // (3072)
    float* out = (float*)d_out;                 // (64,512,1024) fp32

    char* ws = (char*)d_ws;
    size_t off = 0;
    short* XPt   = (short*)(ws + off); off += (size_t)B_ * T_ * G3_ * 2;   // 201.3 MB
    short* Wihbf = (short*)(ws + off); off += (size_t)G3_ * LAT_ * 2;      // 3.1 MB
    short* Whhbf = (short*)(ws + off); off += (size_t)G3_ * HID_ * 2;      // 6.3 MB
    short* Hb0   = (short*)(ws + off); off += (size_t)B_ * HID_ * 2;       // 128 KB
    short* Hb1   = (short*)(ws + off); off += (size_t)B_ * HID_ * 2;       // 128 KB
    int*   slots = (int*)(ws + off);   off += 4096;

    cvt_f2b_kernel<<<(G3_ * LAT_) / 1024, 256, 0, stream>>>(Wih, Wihbf, G3_ * LAT_);
    cvt_f2b_kernel<<<(G3_ * HID_) / 1024, 256, 0, stream>>>(Whh, Whhbf, G3_ * HID_);

    xproj_kernel<<<dim3(24, 256), 256, 0, stream>>>(Z, Wihbf, bih, XPt);

    init_slots<<<1, 256, 0, stream>>>(slots);

    // persistent recurrence: 256 blocks (4 batch-groups x 64 col-blocks),
    // guaranteed co-resident (>=2 blocks/CU by VGPR/LDS limits, 256 CUs).
    gru_persist<<<256, 256, 0, stream>>>(Whhbf, XPt, bhh, Hb0, Hb1, out, slots);
}

// Round 2
// 3670.638 us; speedup vs baseline: 2.4965x; 2.4965x over previous
//
#include <hip/hip_runtime.h>
#include <hip/hip_bf16.h>

// GRU sequence: B=64, T=512, LATENT=512, HIDDEN=1024.
// K0: weights fp32->bf16.  K1: x_proj GEMM, output stored t-major.
// K2: ONE persistent kernel runs all 512 timesteps.
//   Cross-block h exchange uses agent-scope (sc1, LLC-coherent) atomic
//   stores/loads ONLY for h + barrier slots — no buffer_wbl2/buffer_inv
//   L2-wide fences (those cost ~16 us/step in the previous version).

#define B_   64
#define T_   512
#define LAT_ 512
#define HID_ 1024
#define G3_  3072

typedef __bf16  bf8  __attribute__((ext_vector_type(8)));
typedef float   f4   __attribute__((ext_vector_type(4)));
typedef short   s8v  __attribute__((ext_vector_type(8)));
typedef short   s4v  __attribute__((ext_vector_type(4)));

__device__ __forceinline__ bf8 ldb8(const short* p) {
    s8v v = *(const s8v*)p;
    return __builtin_bit_cast(bf8, v);
}
__device__ __forceinline__ float b2f(short s) {
    return __bfloat162float(*(__hip_bfloat16*)&s);
}
__device__ __forceinline__ short f2b(float f) {
    __hip_bfloat16 h = __float2bfloat16(f);
    return *(short*)&h;
}
// agent-coherent (LLC) 16B load built from two 8B relaxed agent atomics (sc1)
__device__ __forceinline__ bf8 ldb8_llc(const short* p) {
    unsigned long long lo = __hip_atomic_load((const unsigned long long*)p,
                                __ATOMIC_RELAXED, __HIP_MEMORY_SCOPE_AGENT);
    unsigned long long hi = __hip_atomic_load((const unsigned long long*)(p + 4),
                                __ATOMIC_RELAXED, __HIP_MEMORY_SCOPE_AGENT);
    ulonglong2 v; v.x = lo; v.y = hi;
    return __builtin_bit_cast(bf8, v);
}

// ---------------------------------------------------------------------------
// K0: fp32 -> bf16 elementwise
// ---------------------------------------------------------------------------
__global__ __launch_bounds__(256) void cvt_f2b_kernel(
    const float* __restrict__ in, short* __restrict__ out, int n)
{
    int i = (blockIdx.x * 256 + threadIdx.x) * 4;
    if (i + 3 < n) {
        f4 v = *(const f4*)(in + i);
        s4v r;
        r.x = f2b(v.x); r.y = f2b(v.y); r.z = f2b(v.z); r.w = f2b(v.w);
        *(s4v*)(out + i) = r;
    }
}

// ---------------------------------------------------------------------------
// K1: XPt[(t*64+b), g] = sum_k Z[b*T+t, k]*Wih[g,k] + bih[g]   (t-major store)
// ---------------------------------------------------------------------------
__global__ __launch_bounds__(256) void xproj_kernel(
    const float* __restrict__ Z,     // (32768, 512) fp32, row = b*T + t
    const short* __restrict__ Wih,   // (3072, 512) bf16
    const float* __restrict__ bih,   // (3072) fp32
    short* __restrict__ XP)          // (32768, 3072) bf16, row = t*B + b
{
    __shared__ short As[128 * 32];
    __shared__ short Bs[128 * 32];

    const int tid  = threadIdx.x;
    const int lane = tid & 63;
    const int wid  = tid >> 6;
    const int wm   = wid & 1;
    const int wn   = wid >> 1;
    const int lrow = lane & 15;
    const int quad = lane >> 4;

    const long arow0 = (long)blockIdx.y * 128;   // M tile base
    const long brow0 = (long)blockIdx.x * 128;   // N tile base

    f4 acc[4][4];
    const f4 zf = {0.f, 0.f, 0.f, 0.f};
#pragma unroll
    for (int i = 0; i < 4; i++)
#pragma unroll
        for (int jj = 0; jj < 4; jj++) acc[i][jj] = zf;

    for (int k0 = 0; k0 < LAT_; k0 += 32) {
#pragma unroll
        for (int i = 0; i < 4; i++) {
            int c   = tid + 256 * i;
            int row = c >> 3;
            int kc  = (c & 7) * 4;
            f4 v = *(const f4*)(Z + (arow0 + row) * LAT_ + k0 + kc);
            s4v r;
            r.x = f2b(v.x); r.y = f2b(v.y); r.z = f2b(v.z); r.w = f2b(v.w);
            *(s4v*)(As + row * 32 + kc) = r;
        }
#pragma unroll
        for (int i = 0; i < 2; i++) {
            int c   = tid + 256 * i;
            int row = c >> 2;
            int kc  = (c & 3) * 8;
            *(s8v*)(Bs + row * 32 + kc) = *(const s8v*)(Wih + (brow0 + row) * LAT_ + k0 + kc);
        }
        __syncthreads();

        bf8 af[4], bfr[4];
#pragma unroll
        for (int mf = 0; mf < 4; mf++)
            af[mf] = ldb8(As + (wm * 64 + mf * 16 + lrow) * 32 + quad * 8);
#pragma unroll
        for (int nf = 0; nf < 4; nf++)
            bfr[nf] = ldb8(Bs + (wn * 64 + nf * 16 + lrow) * 32 + quad * 8);

#pragma unroll
        for (int mf = 0; mf < 4; mf++)
#pragma unroll
            for (int nf = 0; nf < 4; nf++)
                acc[mf][nf] = __builtin_amdgcn_mfma_f32_16x16x32_bf16(
                    af[mf], bfr[nf], acc[mf][nf], 0, 0, 0);
        __syncthreads();
    }

    // epilogue: C/D layout col = lane&15, row = quad*4 + reg. Transposed store.
#pragma unroll
    for (int nf = 0; nf < 4; nf++) {
        int gc = (int)brow0 + wn * 64 + nf * 16 + lrow;
        float bias = bih[gc];
#pragma unroll
        for (int mf = 0; mf < 4; mf++) {
#pragma unroll
            for (int r = 0; r < 4; r++) {
                long gr = arow0 + wm * 64 + mf * 16 + quad * 4 + r;   // b*T + t
                long tr = (gr & (T_ - 1)) * B_ + (gr >> 9);            // t*B + b
                XP[tr * G3_ + gc] = f2b(acc[mf][nf][r] + bias);
            }
        }
    }
}

// ---------------------------------------------------------------------------
// barrier slot init (kernel-end release flushes it to LLC before gru_persist)
// ---------------------------------------------------------------------------
__global__ void init_slots(int* slots) { slots[threadIdx.x] = 0; }

// ---------------------------------------------------------------------------
// K2: persistent GRU recurrence. Grid = 256 blocks x 256 threads.
//   block = (grp = bid>>6: batch rows [grp*16,+16), cb = bid&63: h-cols [cb*16,+16))
//   wave w reduces K-slice [w*256,+256).
//   fp32 h: 1 register/thread. bf16 h shadow: LLC-coherent, double-buffered.
//   One slot-signal barrier per step per batch-group; NO L2-wide fences.
// ---------------------------------------------------------------------------
__global__ __launch_bounds__(256, 2) void gru_persist(
    const short* __restrict__ Whh,   // (3072,1024) bf16
    const short* __restrict__ XPt,   // (T*B,3072) bf16, row = t*64+b
    const float* __restrict__ bhh,   // (3072) fp32
    short* __restrict__ Hb0,         // (64,1024) bf16
    short* __restrict__ Hb1,         // (64,1024) bf16
    float* __restrict__ Out,         // (64,512,1024) fp32
    int*  __restrict__ slots)        // (256) pre-zeroed
{
    __shared__ float red[64 * 50];   // [w*16 + mloc][50] padded (12.8 KB)

    const int tid  = threadIdx.x;
    const int lane = tid & 63;
    const int w    = tid >> 6;
    const int lrow = lane & 15;
    const int quad = lane >> 4;
    const int bid  = blockIdx.x;
    const int grp  = bid >> 6;
    const int cb   = bid & 63;
    const int c0   = cb * 16;
    const int m0   = grp * 16;
    const int kbase = w * 256;
    int* gslots = slots + grp * 64;

    // W_hh B-fragments: 3 gates x 8 k-chunks x 16 cols (cached in L1/L2 now
    // that nothing invalidates them; compiler may re-load per step — fine)
    bf8 bfr[3][8];
#pragma unroll
    for (int g = 0; g < 3; g++)
#pragma unroll
        for (int kk = 0; kk < 8; kk++)
            bfr[g][kk] = ldb8(Whh + (g * HID_ + c0 + lrow) * HID_
                                  + kbase + kk * 32 + quad * 8);

    // per-thread gate element: (mloc = tid>>4, j = tid&15)
    const int mloc = tid >> 4;
    const int j    = tid & 15;
    const int mg   = m0 + mloc;                    // global batch row
    const float br = bhh[c0 + j];
    const float bz = bhh[HID_ + c0 + j];
    const float bn = bhh[2 * HID_ + c0 + j];
    float hfp = 0.f;                               // fp32 h, never leaves regs

    // zero own h0 slice via LLC-coherent u32 stores (even threads store pairs)
    if (!(tid & 1)) {
        unsigned int* hp = (unsigned int*)(Hb0 + mg * HID_ + c0 + j);
        __hip_atomic_store(hp, 0u, __ATOMIC_RELAXED, __HIP_MEMORY_SCOPE_AGENT);
    }

    // prefetch x-proj for t=0 (plain cached loads; XPt is read-only)
    const long tstride = (long)B_ * G3_;
    const short* xpb = XPt + (long)mg * G3_ + c0 + j;
    short xr_s = xpb[0], xz_s = xpb[HID_], xn_s = xpb[2 * HID_];

    // ---- init barrier: h0 visible group-wide (epoch 1) ----
    asm volatile("s_waitcnt vmcnt(0)" ::: "memory");
    __syncthreads();
    if (tid == 0)
        __hip_atomic_store(gslots + cb, 1, __ATOMIC_RELAXED, __HIP_MEMORY_SCOPE_AGENT);
    if (tid < 64) {
        while (__hip_atomic_load(gslots + lane, __ATOMIC_RELAXED,
                                 __HIP_MEMORY_SCOPE_AGENT) < 1)
            __builtin_amdgcn_s_sleep(1);
    }
    __syncthreads();
    asm volatile("" ::: "memory");

#pragma unroll 1
    for (int t = 0; t < T_; t++) {
        const short* Hc = (t & 1) ? Hb1 : Hb0;
        short*       Hn = (t & 1) ? Hb0 : Hb1;

        f4 acc[3];
        const f4 zf = {0.f, 0.f, 0.f, 0.f};
        acc[0] = zf; acc[1] = zf; acc[2] = zf;

        // h reads: LLC-coherent (bypass possibly-stale local L2)
#pragma unroll
        for (int kk = 0; kk < 8; kk++) {
            bf8 a = ldb8_llc(Hc + (m0 + lrow) * HID_ + kbase + kk * 32 + quad * 8);
#pragma unroll
            for (int g = 0; g < 3; g++)
                acc[g] = __builtin_amdgcn_mfma_f32_16x16x32_bf16(
                    a, bfr[g][kk], acc[g], 0, 0, 0);
        }

        // wave partials -> LDS. m = quad*4 + r, col = g*16 + lrow
#pragma unroll
        for (int g = 0; g < 3; g++)
#pragma unroll
            for (int r = 0; r < 4; r++)
                red[(w * 16 + quad * 4 + r) * 50 + g * 16 + lrow] = acc[g][r];
        __syncthreads();

        // cross-wave reduce + gates (1 element/thread)
        float ghr = 0.f, ghz = 0.f, ghn = 0.f;
#pragma unroll
        for (int ww = 0; ww < 4; ww++) {
            const float* rr = red + (ww * 16 + mloc) * 50 + j;
            ghr += rr[0];
            ghz += rr[16];
            ghn += rr[32];
        }

        float rg = 1.f / (1.f + __expf(-(b2f(xr_s) + ghr + br)));
        float ug = 1.f / (1.f + __expf(-(b2f(xz_s) + ghz + bz)));
        float ng = tanhf(b2f(xn_s) + rg * (ghn + bn));
        float hnew = (1.f - ug) * ng + ug * hfp;
        hfp = hnew;

        // h shadow store: pack adjacent cols via shfl, LLC-coherent u32 store
        short hb = f2b(hnew);
        int prt = __shfl_xor((int)hb, 1);
        if (!(tid & 1)) {
            unsigned int pk = (unsigned int)(unsigned short)hb |
                              ((unsigned int)(unsigned short)prt << 16);
            unsigned int* hp = (unsigned int*)(Hn + mg * HID_ + c0 + j);
            __hip_atomic_store(hp, pk, __ATOMIC_RELAXED, __HIP_MEMORY_SCOPE_AGENT);
        }
        Out[((long)mg * T_ + t) * HID_ + c0 + j] = hnew;   // plain; flushed at kernel end

        if (t + 1 < T_) {
            // drain h stores to LLC, then signal
            asm volatile("s_waitcnt vmcnt(0)" ::: "memory");
            __syncthreads();
            if (tid == 0)
                __hip_atomic_store(gslots + cb, t + 2,
                                   __ATOMIC_RELAXED, __HIP_MEMORY_SCOPE_AGENT);
            // prefetch next step's x-proj while waiting (hides cold-HBM latency)
            const short* xp = xpb + (long)(t + 1) * tstride;
            xr_s = xp[0]; xz_s = xp[HID_]; xn_s = xp[2 * HID_];
            if (tid < 64) {
                while (__hip_atomic_load(gslots + lane, __ATOMIC_RELAXED,
                                         __HIP_MEMORY_SCOPE_AGENT) < t + 2)
                    __builtin_amdgcn_s_sleep(1);
            }
            __syncthreads();
            asm volatile("" ::: "memory");
        }
    }
}

extern "C" void kernel_launch(void* const* d_in, const int* in_sizes, int n_in,
                              void* d_out, int out_size, void* d_ws, size_t ws_size,
                              hipStream_t stream) {
    const float* Z   = (const float*)d_in[0];   // (64,512,512)
    const float* Wih = (const float*)d_in[1];   // (3072,512)
    const float* Whh = (const float*)d_in[2];   // (3072,1024)
    const float* bih = (const float*)d_in[3];   // (3072)
    const float* bhh = (const float*)d_in[4];   // (3072)
    float* out = (float*)d_out;                 // (64,512,1024) fp32

    char* ws = (char*)d_ws;
    size_t off = 0;
    short* XPt   = (short*)(ws + off); off += (size_t)B_ * T_ * G3_ * 2;   // 201.3 MB
    short* Wihbf = (short*)(ws + off); off += (size_t)G3_ * LAT_ * 2;      // 3.1 MB
    short* Whhbf = (short*)(ws + off); off += (size_t)G3_ * HID_ * 2;      // 6.3 MB
    short* Hb0   = (short*)(ws + off); off += (size_t)B_ * HID_ * 2;       // 128 KB
    short* Hb1   = (short*)(ws + off); off += (size_t)B_ * HID_ * 2;       // 128 KB
    int*   slots = (int*)(ws + off);   off += 4096;

    cvt_f2b_kernel<<<(G3_ * LAT_) / 1024, 256, 0, stream>>>(Wih, Wihbf, G3_ * LAT_);
    cvt_f2b_kernel<<<(G3_ * HID_) / 1024, 256, 0, stream>>>(Whh, Whhbf, G3_ * HID_);

    xproj_kernel<<<dim3(24, 256), 256, 0, stream>>>(Z, Wihbf, bih, XPt);

    init_slots<<<1, 256, 0, stream>>>(slots);

    // persistent recurrence: 256 blocks (4 batch-groups x 64 col-blocks),
    // co-resident by construction (<=256 blocks, 2 blocks/CU possible).
    gru_persist<<<256, 256, 0, stream>>>(Whhbf, XPt, bhh, Hb0, Hb1, out, slots);
}

// Round 3
// 3408.814 us; speedup vs baseline: 2.6882x; 1.0768x over previous
//
#include <hip/hip_runtime.h>
#include <hip/hip_bf16.h>

// GRU sequence: B=64, T=512, LATENT=512, HIDDEN=1024.
// K0: weights fp32->bf16.  K1: x_proj GEMM, output stored t-major.
// K2: ONE persistent kernel runs all 512 timesteps.
//   - h exchange + flags via agent-scope (LLC-coherent) relaxed atomics only;
//     no L2-wide fences.
//   - per-WAVE producer wait: wave w spins on the 16 flags of the producer
//     blocks covering its K-slice (one cache line), not all 64.
//   - __launch_bounds__(256,1): W_hh fragments stay VGPR-resident (96 VGPRs).
//   - Out store moved off the pre-signal drain path.

#define B_   64
#define T_   512
#define LAT_ 512
#define HID_ 1024
#define G3_  3072

typedef __bf16  bf8  __attribute__((ext_vector_type(8)));
typedef float   f4   __attribute__((ext_vector_type(4)));
typedef short   s8v  __attribute__((ext_vector_type(8)));
typedef short   s4v  __attribute__((ext_vector_type(4)));

__device__ __forceinline__ bf8 ldb8(const short* p) {
    s8v v = *(const s8v*)p;
    return __builtin_bit_cast(bf8, v);
}
__device__ __forceinline__ float b2f(short s) {
    return __bfloat162float(*(__hip_bfloat16*)&s);
}
__device__ __forceinline__ short f2b(float f) {
    __hip_bfloat16 h = __float2bfloat16(f);
    return *(short*)&h;
}
// agent-coherent (LLC) 16B load built from two 8B relaxed agent atomics
__device__ __forceinline__ bf8 ldb8_llc(const short* p) {
    unsigned long long lo = __hip_atomic_load((const unsigned long long*)p,
                                __ATOMIC_RELAXED, __HIP_MEMORY_SCOPE_AGENT);
    unsigned long long hi = __hip_atomic_load((const unsigned long long*)(p + 4),
                                __ATOMIC_RELAXED, __HIP_MEMORY_SCOPE_AGENT);
    ulonglong2 v; v.x = lo; v.y = hi;
    return __builtin_bit_cast(bf8, v);
}

// ---------------------------------------------------------------------------
// K0: fp32 -> bf16 elementwise
// ---------------------------------------------------------------------------
__global__ __launch_bounds__(256) void cvt_f2b_kernel(
    const float* __restrict__ in, short* __restrict__ out, int n)
{
    int i = (blockIdx.x * 256 + threadIdx.x) * 4;
    if (i + 3 < n) {
        f4 v = *(const f4*)(in + i);
        s4v r;
        r.x = f2b(v.x); r.y = f2b(v.y); r.z = f2b(v.z); r.w = f2b(v.w);
        *(s4v*)(out + i) = r;
    }
}

// ---------------------------------------------------------------------------
// K1: XPt[(t*64+b), g] = sum_k Z[b*T+t, k]*Wih[g,k] + bih[g]   (t-major store)
// ---------------------------------------------------------------------------
__global__ __launch_bounds__(256) void xproj_kernel(
    const float* __restrict__ Z,     // (32768, 512) fp32, row = b*T + t
    const short* __restrict__ Wih,   // (3072, 512) bf16
    const float* __restrict__ bih,   // (3072) fp32
    short* __restrict__ XP)          // (32768, 3072) bf16, row = t*B + b
{
    __shared__ short As[128 * 32];
    __shared__ short Bs[128 * 32];

    const int tid  = threadIdx.x;
    const int lane = tid & 63;
    const int wid  = tid >> 6;
    const int wm   = wid & 1;
    const int wn   = wid >> 1;
    const int lrow = lane & 15;
    const int quad = lane >> 4;

    const long arow0 = (long)blockIdx.y * 128;   // M tile base
    const long brow0 = (long)blockIdx.x * 128;   // N tile base

    f4 acc[4][4];
    const f4 zf = {0.f, 0.f, 0.f, 0.f};
#pragma unroll
    for (int i = 0; i < 4; i++)
#pragma unroll
        for (int jj = 0; jj < 4; jj++) acc[i][jj] = zf;

    for (int k0 = 0; k0 < LAT_; k0 += 32) {
#pragma unroll
        for (int i = 0; i < 4; i++) {
            int c   = tid + 256 * i;
            int row = c >> 3;
            int kc  = (c & 7) * 4;
            f4 v = *(const f4*)(Z + (arow0 + row) * LAT_ + k0 + kc);
            s4v r;
            r.x = f2b(v.x); r.y = f2b(v.y); r.z = f2b(v.z); r.w = f2b(v.w);
            *(s4v*)(As + row * 32 + kc) = r;
        }
#pragma unroll
        for (int i = 0; i < 2; i++) {
            int c   = tid + 256 * i;
            int row = c >> 2;
            int kc  = (c & 3) * 8;
            *(s8v*)(Bs + row * 32 + kc) = *(const s8v*)(Wih + (brow0 + row) * LAT_ + k0 + kc);
        }
        __syncthreads();

        bf8 af[4], bfr[4];
#pragma unroll
        for (int mf = 0; mf < 4; mf++)
            af[mf] = ldb8(As + (wm * 64 + mf * 16 + lrow) * 32 + quad * 8);
#pragma unroll
        for (int nf = 0; nf < 4; nf++)
            bfr[nf] = ldb8(Bs + (wn * 64 + nf * 16 + lrow) * 32 + quad * 8);

#pragma unroll
        for (int mf = 0; mf < 4; mf++)
#pragma unroll
            for (int nf = 0; nf < 4; nf++)
                acc[mf][nf] = __builtin_amdgcn_mfma_f32_16x16x32_bf16(
                    af[mf], bfr[nf], acc[mf][nf], 0, 0, 0);
        __syncthreads();
    }

    // epilogue: C/D layout col = lane&15, row = quad*4 + reg. Transposed store.
#pragma unroll
    for (int nf = 0; nf < 4; nf++) {
        int gc = (int)brow0 + wn * 64 + nf * 16 + lrow;
        float bias = bih[gc];
#pragma unroll
        for (int mf = 0; mf < 4; mf++) {
#pragma unroll
            for (int r = 0; r < 4; r++) {
                long gr = arow0 + wm * 64 + mf * 16 + quad * 4 + r;   // b*T + t
                long tr = (gr & (T_ - 1)) * B_ + (gr >> 9);            // t*B + b
                XP[tr * G3_ + gc] = f2b(acc[mf][nf][r] + bias);
            }
        }
    }
}

// ---------------------------------------------------------------------------
// barrier slot init
// ---------------------------------------------------------------------------
__global__ void init_slots(int* slots) { slots[threadIdx.x] = 0; }

// ---------------------------------------------------------------------------
// K2: persistent GRU recurrence. Grid = 256 blocks x 256 threads.
//   block = (grp = bid>>6: batch rows [grp*16,+16), cb = bid&63: h-cols [cb*16,+16))
//   wave w reduces K-slice [w*256,+256); waits only on its 16 producers.
// ---------------------------------------------------------------------------
__global__ __launch_bounds__(256, 1) void gru_persist(
    const short* __restrict__ Whh,   // (3072,1024) bf16
    const short* __restrict__ XPt,   // (T*B,3072) bf16, row = t*64+b
    const float* __restrict__ bhh,   // (3072) fp32
    short* __restrict__ Hb0,         // (64,1024) bf16
    short* __restrict__ Hb1,         // (64,1024) bf16
    float* __restrict__ Out,         // (64,512,1024) fp32
    int*  __restrict__ slots)        // (256) pre-zeroed
{
    __shared__ float red[64 * 50];   // [w*16 + mloc][50] padded (12.8 KB)

    const int tid  = threadIdx.x;
    const int lane = tid & 63;
    const int w    = tid >> 6;
    const int lrow = lane & 15;
    const int quad = lane >> 4;
    const int bid  = blockIdx.x;
    const int grp  = bid >> 6;
    const int cb   = bid & 63;
    const int c0   = cb * 16;
    const int m0   = grp * 16;
    const int kbase = w * 256;
    int* gslots = slots + grp * 64;
    // wave w consumes cols [w*256, w*256+256) -> producers cb in [w*16, w*16+16)
    int* myflag = gslots + w * 16 + (lane & 15);

    // W_hh B-fragments pinned in VGPRs: 3 gates x 8 k-chunks (96 VGPRs)
    bf8 bfr[3][8];
#pragma unroll
    for (int g = 0; g < 3; g++)
#pragma unroll
        for (int kk = 0; kk < 8; kk++)
            bfr[g][kk] = ldb8(Whh + (g * HID_ + c0 + lrow) * HID_
                                  + kbase + kk * 32 + quad * 8);

    // per-thread gate element: (mloc = tid>>4, j = tid&15)
    const int mloc = tid >> 4;
    const int j    = tid & 15;
    const int mg   = m0 + mloc;                    // global batch row
    const float br = bhh[c0 + j];
    const float bz = bhh[HID_ + c0 + j];
    const float bn = bhh[2 * HID_ + c0 + j];
    float hfp = 0.f;                               // fp32 h, never leaves regs

    // zero own h0 slice via LLC-coherent u32 stores (even threads store pairs)
    if (!(tid & 1)) {
        unsigned int* hp = (unsigned int*)(Hb0 + mg * HID_ + c0 + j);
        __hip_atomic_store(hp, 0u, __ATOMIC_RELAXED, __HIP_MEMORY_SCOPE_AGENT);
    }

    // prefetch x-proj for t=0 (plain cached loads; XPt is read-only)
    const long tstride = (long)B_ * G3_;
    const short* xpb = XPt + (long)mg * G3_ + c0 + j;
    short xr_s = xpb[0], xz_s = xpb[HID_], xn_s = xpb[2 * HID_];

    // signal h0 ready (epoch 1)
    asm volatile("s_waitcnt vmcnt(0)" ::: "memory");
    __syncthreads();
    if (tid == 0)
        __hip_atomic_store(gslots + cb, 1, __ATOMIC_RELAXED, __HIP_MEMORY_SCOPE_AGENT);

#pragma unroll 1
    for (int t = 0; t < T_; t++) {
        const short* Hc = (t & 1) ? Hb1 : Hb0;
        short*       Hn = (t & 1) ? Hb0 : Hb1;

        // per-wave wait: my 16 producers have published h_t (epoch t+1)
        while (true) {
            int v = __hip_atomic_load(myflag, __ATOMIC_RELAXED,
                                      __HIP_MEMORY_SCOPE_AGENT);
            if (__all(v >= t + 1)) break;
        }

        f4 acc[3];
        const f4 zf = {0.f, 0.f, 0.f, 0.f};
        acc[0] = zf; acc[1] = zf; acc[2] = zf;

        // h reads: LLC-coherent (bypass possibly-stale local caches)
#pragma unroll
        for (int kk = 0; kk < 8; kk++) {
            bf8 a = ldb8_llc(Hc + (m0 + lrow) * HID_ + kbase + kk * 32 + quad * 8);
#pragma unroll
            for (int g = 0; g < 3; g++)
                acc[g] = __builtin_amdgcn_mfma_f32_16x16x32_bf16(
                    a, bfr[g][kk], acc[g], 0, 0, 0);
        }

        // wave partials -> LDS. m = quad*4 + r, col = g*16 + lrow
#pragma unroll
        for (int g = 0; g < 3; g++)
#pragma unroll
            for (int r = 0; r < 4; r++)
                red[(w * 16 + quad * 4 + r) * 50 + g * 16 + lrow] = acc[g][r];
        __syncthreads();

        // cross-wave reduce + gates (1 element/thread)
        float ghr = 0.f, ghz = 0.f, ghn = 0.f;
#pragma unroll
        for (int ww = 0; ww < 4; ww++) {
            const float* rr = red + (ww * 16 + mloc) * 50 + j;
            ghr += rr[0];
            ghz += rr[16];
            ghn += rr[32];
        }

        float rg = 1.f / (1.f + __expf(-(b2f(xr_s) + ghr + br)));
        float ug = 1.f / (1.f + __expf(-(b2f(xz_s) + ghz + bz)));
        float ng = tanhf(b2f(xn_s) + rg * (ghn + bn));
        float hnew = (1.f - ug) * ng + ug * hfp;
        hfp = hnew;

        // h shadow store: pack adjacent cols via shfl, LLC-coherent u32 store
        short hb = f2b(hnew);
        int prt = __shfl_xor((int)hb, 1);
        if (!(tid & 1)) {
            unsigned int pk = (unsigned int)(unsigned short)hb |
                              ((unsigned int)(unsigned short)prt << 16);
            unsigned int* hp = (unsigned int*)(Hn + mg * HID_ + c0 + j);
            __hip_atomic_store(hp, pk, __ATOMIC_RELAXED, __HIP_MEMORY_SCOPE_AGENT);
        }

        // drain h stores to LLC, then signal h_{t+1} ready (epoch t+2).
        // (Out store intentionally issued AFTER the drain+signal.)
        asm volatile("s_waitcnt vmcnt(0)" ::: "memory");
        __syncthreads();   // also separates red[] read (gates) from next write
        if (t + 1 < T_) {
            if (tid == 0)
                __hip_atomic_store(gslots + cb, t + 2,
                                   __ATOMIC_RELAXED, __HIP_MEMORY_SCOPE_AGENT);
        }

        Out[((long)mg * T_ + t) * HID_ + c0 + j] = hnew;

        if (t + 1 < T_) {
            // prefetch next step's x-proj (cold HBM; hides under next wait)
            const short* xp = xpb + (long)(t + 1) * tstride;
            xr_s = xp[0]; xz_s = xp[HID_]; xn_s = xp[2 * HID_];
        }
    }
}

extern "C" void kernel_launch(void* const* d_in, const int* in_sizes, int n_in,
                              void* d_out, int out_size, void* d_ws, size_t ws_size,
                              hipStream_t stream) {
    const float* Z   = (const float*)d_in[0];   // (64,512,512)
    const float* Wih = (const float*)d_in[1];   // (3072,512)
    const float* Whh = (const float*)d_in[2];   // (3072,1024)
    const float* bih = (const float*)d_in[3];   // (3072)
    const float* bhh = (const float*)d_in[4];   // (3072)
    float* out = (float*)d_out;                 // (64,512,1024) fp32

    char* ws = (char*)d_ws;
    size_t off = 0;
    short* XPt   = (short*)(ws + off); off += (size_t)B_ * T_ * G3_ * 2;   // 201.3 MB
    short* Wihbf = (short*)(ws + off); off += (size_t)G3_ * LAT_ * 2;      // 3.1 MB
    short* Whhbf = (short*)(ws + off); off += (size_t)G3_ * HID_ * 2;      // 6.3 MB
    short* Hb0   = (short*)(ws + off); off += (size_t)B_ * HID_ * 2;       // 128 KB
    short* Hb1   = (short*)(ws + off); off += (size_t)B_ * HID_ * 2;       // 128 KB
    int*   slots = (int*)(ws + off);   off += 4096;

    cvt_f2b_kernel<<<(G3_ * LAT_) / 1024, 256, 0, stream>>>(Wih, Wihbf, G3_ * LAT_);
    cvt_f2b_kernel<<<(G3_ * HID_) / 1024, 256, 0, stream>>>(Whh, Whhbf, G3_ * HID_);

    xproj_kernel<<<dim3(24, 256), 256, 0, stream>>>(Z, Wihbf, bih, XPt);

    init_slots<<<1, 256, 0, stream>>>(slots);

    // persistent recurrence: 256 blocks (4 batch-groups x 64 col-blocks),
    // one block per CU.
    gru_persist<<<256, 256, 0, stream>>>(Whhbf, XPt, bhh, Hb0, Hb1, out, slots);
}

// Round 4
// 3135.175 us; speedup vs baseline: 2.9228x; 1.0873x over previous
//
#include <hip/hip_runtime.h>
#include <hip/hip_bf16.h>

// GRU sequence: B=64, T=512, LATENT=512, HIDDEN=1024.
// K0: weights fp32->bf16.  K1: x_proj GEMM (b_ih + b_hh[r,z] folded in),
//     output stored t-major.
// K2: ONE persistent kernel runs all 512 timesteps.
//   - h exchange + flags via agent-scope (LLC) relaxed atomics; no L2 fences.
//   - per-WAVE producer wait (16 flags = one cache line).
//   - W_hh block slice staged ONCE into LDS (96 KB, XOR-swizzled): per-step
//     W access is ds_read_b128 — immune to the per-step asm memory clobbers
//     that forced global W re-loads (VGPR=80 evidence in round 3).
//   - fast tanh via __expf (precise tanhf libcall was on the critical path).

#define B_   64
#define T_   512
#define LAT_ 512
#define HID_ 1024
#define G3_  3072

typedef __bf16  bf8  __attribute__((ext_vector_type(8)));
typedef float   f4   __attribute__((ext_vector_type(4)));
typedef short   s8v  __attribute__((ext_vector_type(8)));
typedef short   s4v  __attribute__((ext_vector_type(4)));

__device__ __forceinline__ bf8 ldb8(const short* p) {
    s8v v = *(const s8v*)p;
    return __builtin_bit_cast(bf8, v);
}
__device__ __forceinline__ float b2f(short s) {
    return __bfloat162float(*(__hip_bfloat16*)&s);
}
__device__ __forceinline__ short f2b(float f) {
    __hip_bfloat16 h = __float2bfloat16(f);
    return *(short*)&h;
}
// agent-coherent (LLC) 16B load built from two 8B relaxed agent atomics
__device__ __forceinline__ bf8 ldb8_llc(const short* p) {
    unsigned long long lo = __hip_atomic_load((const unsigned long long*)p,
                                __ATOMIC_RELAXED, __HIP_MEMORY_SCOPE_AGENT);
    unsigned long long hi = __hip_atomic_load((const unsigned long long*)(p + 4),
                                __ATOMIC_RELAXED, __HIP_MEMORY_SCOPE_AGENT);
    ulonglong2 v; v.x = lo; v.y = hi;
    return __builtin_bit_cast(bf8, v);
}

// ---------------------------------------------------------------------------
// K0: fp32 -> bf16 elementwise
// ---------------------------------------------------------------------------
__global__ __launch_bounds__(256) void cvt_f2b_kernel(
    const float* __restrict__ in, short* __restrict__ out, int n)
{
    int i = (blockIdx.x * 256 + threadIdx.x) * 4;
    if (i + 3 < n) {
        f4 v = *(const f4*)(in + i);
        s4v r;
        r.x = f2b(v.x); r.y = f2b(v.y); r.z = f2b(v.z); r.w = f2b(v.w);
        *(s4v*)(out + i) = r;
    }
}

// ---------------------------------------------------------------------------
// K1: XPt[(t*64+b), g] = sum_k Z[b*T+t, k]*Wih[g,k] + bih[g] (+bhh[g] if g<2H)
// ---------------------------------------------------------------------------
__global__ __launch_bounds__(256) void xproj_kernel(
    const float* __restrict__ Z,     // (32768, 512) fp32, row = b*T + t
    const short* __restrict__ Wih,   // (3072, 512) bf16
    const float* __restrict__ bih,   // (3072) fp32
    const float* __restrict__ bhh,   // (3072) fp32
    short* __restrict__ XP)          // (32768, 3072) bf16, row = t*B + b
{
    __shared__ short As[128 * 32];
    __shared__ short Bs[128 * 32];

    const int tid  = threadIdx.x;
    const int lane = tid & 63;
    const int wid  = tid >> 6;
    const int wm   = wid & 1;
    const int wn   = wid >> 1;
    const int lrow = lane & 15;
    const int quad = lane >> 4;

    const long arow0 = (long)blockIdx.y * 128;   // M tile base
    const long brow0 = (long)blockIdx.x * 128;   // N tile base

    f4 acc[4][4];
    const f4 zf = {0.f, 0.f, 0.f, 0.f};
#pragma unroll
    for (int i = 0; i < 4; i++)
#pragma unroll
        for (int jj = 0; jj < 4; jj++) acc[i][jj] = zf;

    for (int k0 = 0; k0 < LAT_; k0 += 32) {
#pragma unroll
        for (int i = 0; i < 4; i++) {
            int c   = tid + 256 * i;
            int row = c >> 3;
            int kc  = (c & 7) * 4;
            f4 v = *(const f4*)(Z + (arow0 + row) * LAT_ + k0 + kc);
            s4v r;
            r.x = f2b(v.x); r.y = f2b(v.y); r.z = f2b(v.z); r.w = f2b(v.w);
            *(s4v*)(As + row * 32 + kc) = r;
        }
#pragma unroll
        for (int i = 0; i < 2; i++) {
            int c   = tid + 256 * i;
            int row = c >> 2;
            int kc  = (c & 3) * 8;
            *(s8v*)(Bs + row * 32 + kc) = *(const s8v*)(Wih + (brow0 + row) * LAT_ + k0 + kc);
        }
        __syncthreads();

        bf8 af[4], bfr[4];
#pragma unroll
        for (int mf = 0; mf < 4; mf++)
            af[mf] = ldb8(As + (wm * 64 + mf * 16 + lrow) * 32 + quad * 8);
#pragma unroll
        for (int nf = 0; nf < 4; nf++)
            bfr[nf] = ldb8(Bs + (wn * 64 + nf * 16 + lrow) * 32 + quad * 8);

#pragma unroll
        for (int mf = 0; mf < 4; mf++)
#pragma unroll
            for (int nf = 0; nf < 4; nf++)
                acc[mf][nf] = __builtin_amdgcn_mfma_f32_16x16x32_bf16(
                    af[mf], bfr[nf], acc[mf][nf], 0, 0, 0);
        __syncthreads();
    }

    // epilogue: C/D layout col = lane&15, row = quad*4 + reg. Transposed store.
#pragma unroll
    for (int nf = 0; nf < 4; nf++) {
        int gc = (int)brow0 + wn * 64 + nf * 16 + lrow;
        float bias = bih[gc] + ((gc < 2 * HID_) ? bhh[gc] : 0.f);  // fold r,z b_hh
#pragma unroll
        for (int mf = 0; mf < 4; mf++) {
#pragma unroll
            for (int r = 0; r < 4; r++) {
                long gr = arow0 + wm * 64 + mf * 16 + quad * 4 + r;   // b*T + t
                long tr = (gr & (T_ - 1)) * B_ + (gr >> 9);            // t*B + b
                XP[tr * G3_ + gc] = f2b(acc[mf][nf][r] + bias);
            }
        }
    }
}

// ---------------------------------------------------------------------------
// barrier slot init
// ---------------------------------------------------------------------------
__global__ void init_slots(int* slots) { slots[threadIdx.x] = 0; }

// ---------------------------------------------------------------------------
// K2: persistent GRU recurrence. Grid = 256 blocks x 256 threads.
//   block = (grp = bid>>6: batch rows [grp*16,+16), cb = bid&63: h-cols [cb*16,+16))
//   wave w reduces K-slice [w*256,+256); waits only on its 16 producers.
// ---------------------------------------------------------------------------
__global__ __launch_bounds__(256, 1) void gru_persist(
    const short* __restrict__ Whh,   // (3072,1024) bf16
    const short* __restrict__ XPt,   // (T*B,3072) bf16, row = t*64+b
    const float* __restrict__ bhh,   // (3072) fp32
    short* __restrict__ Hb0,         // (64,1024) bf16
    short* __restrict__ Hb1,         // (64,1024) bf16
    float* __restrict__ Out,         // (64,512,1024) fp32
    int*  __restrict__ slots)        // (256) pre-zeroed
{
    __shared__ short Wlds[48 * 1024];   // 96 KB: block's W slice, swizzled
    __shared__ float red[64 * 50];      // 12.8 KB
    __shared__ float bnl[16];           // b_hh n-gate slice

    const int tid  = threadIdx.x;
    const int lane = tid & 63;
    const int w    = tid >> 6;
    const int lrow = lane & 15;
    const int quad = lane >> 4;
    const int bid  = blockIdx.x;
    const int grp  = bid >> 6;
    const int cb   = bid & 63;
    const int c0   = cb * 16;
    const int m0   = grp * 16;
    const int kbase = w * 256;
    int* gslots = slots + grp * 64;
    // wave w consumes cols [w*256, w*256+256) -> producers cb in [w*16, w*16+16)
    int* myflag = gslots + w * 16 + (lane & 15);

    // ---- stage W slice into LDS (once). chunk c: row=c>>7, slot=c&127.
    // LDS 16B slot address swizzle: slot' = slot ^ (row&15)  (bank-spread)
#pragma unroll
    for (int i = 0; i < 24; i++) {
        int c    = tid + 256 * i;
        int row  = c >> 7;
        int slot = c & 127;
        int g    = row >> 4;
        int r16  = row & 15;
        const short* src = Whh + ((long)(g * HID_ + c0 + r16)) * HID_ + slot * 8;
        *(s8v*)(Wlds + row * 1024 + ((slot ^ r16) << 3)) = *(const s8v*)src;
    }
    if (tid < 16) bnl[tid] = bhh[2 * HID_ + c0 + tid];

    // per-thread gate element: (mloc = tid>>4, j = tid&15)
    const int mloc = tid >> 4;
    const int j    = tid & 15;
    const int mg   = m0 + mloc;                    // global batch row
    float hfp = 0.f;                               // fp32 h, never leaves regs

    // zero own h0 slice via LLC-coherent u32 stores (even threads store pairs)
    if (!(tid & 1)) {
        unsigned int* hp = (unsigned int*)(Hb0 + mg * HID_ + c0 + j);
        __hip_atomic_store(hp, 0u, __ATOMIC_RELAXED, __HIP_MEMORY_SCOPE_AGENT);
    }

    // prefetch x-proj for t=0 (plain cached loads; XPt is read-only)
    const long tstride = (long)B_ * G3_;
    const short* xpb = XPt + (long)mg * G3_ + c0 + j;
    short xr_s = xpb[0], xz_s = xpb[HID_], xn_s = xpb[2 * HID_];

    // signal h0 ready (epoch 1); also covers LDS staging via the barrier
    asm volatile("s_waitcnt vmcnt(0)" ::: "memory");
    __syncthreads();
    if (tid == 0)
        __hip_atomic_store(gslots + cb, 1, __ATOMIC_RELAXED, __HIP_MEMORY_SCOPE_AGENT);

#pragma unroll 1
    for (int t = 0; t < T_; t++) {
        const short* Hc = (t & 1) ? Hb1 : Hb0;
        short*       Hn = (t & 1) ? Hb0 : Hb1;

        // per-wave wait: my 16 producers have published h_t (epoch t+1)
        while (true) {
            int v = __hip_atomic_load(myflag, __ATOMIC_RELAXED,
                                      __HIP_MEMORY_SCOPE_AGENT);
            if (__all(v >= t + 1)) break;
        }

        // batch-issue all 8 h fragments (LLC loads pipeline)
        bf8 a[8];
#pragma unroll
        for (int kk = 0; kk < 8; kk++)
            a[kk] = ldb8_llc(Hc + (m0 + lrow) * HID_ + kbase + kk * 32 + quad * 8);

        f4 acc[3];
        const f4 zf = {0.f, 0.f, 0.f, 0.f};
        acc[0] = zf; acc[1] = zf; acc[2] = zf;

        // W from LDS (swizzled slots); 3 ds_read_b128 + 3 MFMA per kk
#pragma unroll
        for (int kk = 0; kk < 8; kk++) {
            int slotIdx = w * 32 + kk * 4 + quad;
            int swz = (slotIdx ^ lrow) << 3;
#pragma unroll
            for (int g = 0; g < 3; g++) {
                bf8 wf = ldb8(Wlds + (g * 16 + lrow) * 1024 + swz);
                acc[g] = __builtin_amdgcn_mfma_f32_16x16x32_bf16(
                    a[kk], wf, acc[g], 0, 0, 0);
            }
        }

        // wave partials -> LDS. m = quad*4 + r, col = g*16 + lrow
#pragma unroll
        for (int g = 0; g < 3; g++)
#pragma unroll
            for (int r = 0; r < 4; r++)
                red[(w * 16 + quad * 4 + r) * 50 + g * 16 + lrow] = acc[g][r];
        __syncthreads();

        // cross-wave reduce + gates (1 element/thread)
        float ghr = 0.f, ghz = 0.f, ghn = 0.f;
#pragma unroll
        for (int ww = 0; ww < 4; ww++) {
            const float* rr = red + (ww * 16 + mloc) * 50 + j;
            ghr += rr[0];
            ghz += rr[16];
            ghn += rr[32];
        }

        float rg = 1.f / (1.f + __expf(-(b2f(xr_s) + ghr)));   // b_ih+b_hh folded
        float ug = 1.f / (1.f + __expf(-(b2f(xz_s) + ghz)));
        float xa = b2f(xn_s) + rg * (ghn + bnl[j]);
        float e  = __expf(-2.f * fabsf(xa));                   // fast tanh, no overflow
        float ng = copysignf((1.f - e) / (1.f + e), xa);
        float hnew = (1.f - ug) * ng + ug * hfp;
        hfp = hnew;

        // h shadow store: pack adjacent cols via shfl, LLC-coherent u32 store
        short hb = f2b(hnew);
        int prt = __shfl_xor((int)hb, 1);
        if (!(tid & 1)) {
            unsigned int pk = (unsigned int)(unsigned short)hb |
                              ((unsigned int)(unsigned short)prt << 16);
            unsigned int* hp = (unsigned int*)(Hn + mg * HID_ + c0 + j);
            __hip_atomic_store(hp, pk, __ATOMIC_RELAXED, __HIP_MEMORY_SCOPE_AGENT);
        }

        // drain h stores to LLC, then signal h_{t+1} ready (epoch t+2).
        asm volatile("s_waitcnt vmcnt(0)" ::: "memory");
        __syncthreads();   // all waves drained; also guards red[] reuse
        if (t + 1 < T_) {
            if (tid == 0)
                __hip_atomic_store(gslots + cb, t + 2,
                                   __ATOMIC_RELAXED, __HIP_MEMORY_SCOPE_AGENT);
        }

        Out[((long)mg * T_ + t) * HID_ + c0 + j] = hnew;

        if (t + 1 < T_) {
            const short* xp = xpb + (long)(t + 1) * tstride;
            xr_s = xp[0]; xz_s = xp[HID_]; xn_s = xp[2 * HID_];
        }
    }
}

extern "C" void kernel_launch(void* const* d_in, const int* in_sizes, int n_in,
                              void* d_out, int out_size, void* d_ws, size_t ws_size,
                              hipStream_t stream) {
    const float* Z   = (const float*)d_in[0];   // (64,512,512)
    const float* Wih = (const float*)d_in[1];   // (3072,512)
    const float* Whh = (const float*)d_in[2];   // (3072,1024)
    const float* bih = (const float*)d_in[3];   // (3072)
    const float* bhh = (const float*)d_in[4];   // (3072)
    float* out = (float*)d_out;                 // (64,512,1024) fp32

    char* ws = (char*)d_ws;
    size_t off = 0;
    short* XPt   = (short*)(ws + off); off += (size_t)B_ * T_ * G3_ * 2;   // 201.3 MB
    short* Wihbf = (short*)(ws + off); off += (size_t)G3_ * LAT_ * 2;      // 3.1 MB
    short* Whhbf = (short*)(ws + off); off += (size_t)G3_ * HID_ * 2;      // 6.3 MB
    short* Hb0   = (short*)(ws + off); off += (size_t)B_ * HID_ * 2;       // 128 KB
    short* Hb1   = (short*)(ws + off); off += (size_t)B_ * HID_ * 2;       // 128 KB
    int*   slots = (int*)(ws + off);   off += 4096;

    cvt_f2b_kernel<<<(G3_ * LAT_) / 1024, 256, 0, stream>>>(Wih, Wihbf, G3_ * LAT_);
    cvt_f2b_kernel<<<(G3_ * HID_) / 1024, 256, 0, stream>>>(Whh, Whhbf, G3_ * HID_);

    xproj_kernel<<<dim3(24, 256), 256, 0, stream>>>(Z, Wihbf, bih, bhh, XPt);

    init_slots<<<1, 256, 0, stream>>>(slots);

    // persistent recurrence: 256 blocks (4 batch-groups x 64 col-blocks),
    // one block per CU (LDS 108.8 KB/block).
    gru_persist<<<256, 256, 0, stream>>>(Whhbf, XPt, bhh, Hb0, Hb1, out, slots);
}

// Round 5
// 2408.798 us; speedup vs baseline: 3.8042x; 1.3016x over previous
//
#include <hip/hip_runtime.h>
#include <hip/hip_bf16.h>

// GRU sequence: B=64, T=512, LATENT=512, HIDDEN=1024.
// K0: weights fp32->bf16.  K1: x_proj GEMM (b_ih + b_hh[r,z] folded in),
//     output stored t-major.
// K2: ONE persistent kernel runs all 512 timesteps.
//   - h exchange + flags via agent-scope (LLC) relaxed atomics; no L2 fences.
//   - PER-WAVE flags (4/block): wave drains own stores then signals; no
//     post-drain __syncthreads, no tid0 fan-in hop.
//   - h ring buffer x4 (write-after-read safety via poll-graph transitivity:
//     wave enters iter t => all waves completed t-2; ring-4 read at t-3 done).
//   - red[] double-buffered (t&1); single __syncthreads per iteration.
//   - XP prefetch issued right after h-loads (hidden under MFMA+reduce);
//     Out store before drain; poll loop has only the flag load outstanding.
//   - W_hh slice staged once in LDS (96 KB, XOR-swizzled 16B slots).

#define B_   64
#define T_   512
#define LAT_ 512
#define HID_ 1024
#define G3_  3072

typedef __bf16  bf8  __attribute__((ext_vector_type(8)));
typedef float   f4   __attribute__((ext_vector_type(4)));
typedef short   s8v  __attribute__((ext_vector_type(8)));
typedef short   s4v  __attribute__((ext_vector_type(4)));

__device__ __forceinline__ bf8 ldb8(const short* p) {
    s8v v = *(const s8v*)p;
    return __builtin_bit_cast(bf8, v);
}
__device__ __forceinline__ float b2f(short s) {
    return __bfloat162float(*(__hip_bfloat16*)&s);
}
__device__ __forceinline__ short f2b(float f) {
    __hip_bfloat16 h = __float2bfloat16(f);
    return *(short*)&h;
}
// agent-coherent (LLC) 16B load built from two 8B relaxed agent atomics
__device__ __forceinline__ bf8 ldb8_llc(const short* p) {
    unsigned long long lo = __hip_atomic_load((const unsigned long long*)p,
                                __ATOMIC_RELAXED, __HIP_MEMORY_SCOPE_AGENT);
    unsigned long long hi = __hip_atomic_load((const unsigned long long*)(p + 4),
                                __ATOMIC_RELAXED, __HIP_MEMORY_SCOPE_AGENT);
    ulonglong2 v; v.x = lo; v.y = hi;
    return __builtin_bit_cast(bf8, v);
}

// ---------------------------------------------------------------------------
// K0: fp32 -> bf16 elementwise
// ---------------------------------------------------------------------------
__global__ __launch_bounds__(256) void cvt_f2b_kernel(
    const float* __restrict__ in, short* __restrict__ out, int n)
{
    int i = (blockIdx.x * 256 + threadIdx.x) * 4;
    if (i + 3 < n) {
        f4 v = *(const f4*)(in + i);
        s4v r;
        r.x = f2b(v.x); r.y = f2b(v.y); r.z = f2b(v.z); r.w = f2b(v.w);
        *(s4v*)(out + i) = r;
    }
}

// ---------------------------------------------------------------------------
// K1: XPt[(t*64+b), g] = sum_k Z[b*T+t, k]*Wih[g,k] + bih[g] (+bhh[g] if g<2H)
// ---------------------------------------------------------------------------
__global__ __launch_bounds__(256) void xproj_kernel(
    const float* __restrict__ Z,     // (32768, 512) fp32, row = b*T + t
    const short* __restrict__ Wih,   // (3072, 512) bf16
    const float* __restrict__ bih,   // (3072) fp32
    const float* __restrict__ bhh,   // (3072) fp32
    short* __restrict__ XP)          // (32768, 3072) bf16, row = t*B + b
{
    __shared__ short As[128 * 32];
    __shared__ short Bs[128 * 32];

    const int tid  = threadIdx.x;
    const int lane = tid & 63;
    const int wid  = tid >> 6;
    const int wm   = wid & 1;
    const int wn   = wid >> 1;
    const int lrow = lane & 15;
    const int quad = lane >> 4;

    const long arow0 = (long)blockIdx.y * 128;   // M tile base
    const long brow0 = (long)blockIdx.x * 128;   // N tile base

    f4 acc[4][4];
    const f4 zf = {0.f, 0.f, 0.f, 0.f};
#pragma unroll
    for (int i = 0; i < 4; i++)
#pragma unroll
        for (int jj = 0; jj < 4; jj++) acc[i][jj] = zf;

    for (int k0 = 0; k0 < LAT_; k0 += 32) {
#pragma unroll
        for (int i = 0; i < 4; i++) {
            int c   = tid + 256 * i;
            int row = c >> 3;
            int kc  = (c & 7) * 4;
            f4 v = *(const f4*)(Z + (arow0 + row) * LAT_ + k0 + kc);
            s4v r;
            r.x = f2b(v.x); r.y = f2b(v.y); r.z = f2b(v.z); r.w = f2b(v.w);
            *(s4v*)(As + row * 32 + kc) = r;
        }
#pragma unroll
        for (int i = 0; i < 2; i++) {
            int c   = tid + 256 * i;
            int row = c >> 2;
            int kc  = (c & 3) * 8;
            *(s8v*)(Bs + row * 32 + kc) = *(const s8v*)(Wih + (brow0 + row) * LAT_ + k0 + kc);
        }
        __syncthreads();

        bf8 af[4], bfr[4];
#pragma unroll
        for (int mf = 0; mf < 4; mf++)
            af[mf] = ldb8(As + (wm * 64 + mf * 16 + lrow) * 32 + quad * 8);
#pragma unroll
        for (int nf = 0; nf < 4; nf++)
            bfr[nf] = ldb8(Bs + (wn * 64 + nf * 16 + lrow) * 32 + quad * 8);

#pragma unroll
        for (int mf = 0; mf < 4; mf++)
#pragma unroll
            for (int nf = 0; nf < 4; nf++)
                acc[mf][nf] = __builtin_amdgcn_mfma_f32_16x16x32_bf16(
                    af[mf], bfr[nf], acc[mf][nf], 0, 0, 0);
        __syncthreads();
    }

    // epilogue: C/D layout col = lane&15, row = quad*4 + reg. Transposed store.
#pragma unroll
    for (int nf = 0; nf < 4; nf++) {
        int gc = (int)brow0 + wn * 64 + nf * 16 + lrow;
        float bias = bih[gc] + ((gc < 2 * HID_) ? bhh[gc] : 0.f);  // fold r,z b_hh
#pragma unroll
        for (int mf = 0; mf < 4; mf++) {
#pragma unroll
            for (int r = 0; r < 4; r++) {
                long gr = arow0 + wm * 64 + mf * 16 + quad * 4 + r;   // b*T + t
                long tr = (gr & (T_ - 1)) * B_ + (gr >> 9);            // t*B + b
                XP[tr * G3_ + gc] = f2b(acc[mf][nf][r] + bias);
            }
        }
    }
}

// ---------------------------------------------------------------------------
// flag init: 4 groups x 64 blocks x 4 waves = 1024 ints
// ---------------------------------------------------------------------------
__global__ void init_slots(int* slots) { slots[blockIdx.x * 256 + threadIdx.x] = 0; }

// ---------------------------------------------------------------------------
// K2: persistent GRU recurrence. Grid = 256 blocks x 256 threads.
//   block = (grp = bid>>6: batch rows [grp*16,+16), cb = bid&63: h-cols [cb*16,+16))
//   wave w reduces K-slice [w*256,+256); polls 64 producer-WAVE flags.
// ---------------------------------------------------------------------------
__global__ __launch_bounds__(256, 1) void gru_persist(
    const short* __restrict__ Whh,   // (3072,1024) bf16
    const short* __restrict__ XPt,   // (T*B,3072) bf16, row = t*64+b
    const float* __restrict__ bhh,   // (3072) fp32
    short* __restrict__ Hring,       // 4 x (64,1024) bf16, buf i at +i*65536
    float* __restrict__ Out,         // (64,512,1024) fp32
    int*  __restrict__ slots)        // (4*256) pre-zeroed, [grp][blk*4+wave]
{
    __shared__ short Wlds[48 * 1024];   // 96 KB: block's W slice, swizzled
    __shared__ float red[2][64 * 50];   // 25.6 KB, double-buffered
    __shared__ float bnl[16];           // b_hh n-gate slice

    const int tid  = threadIdx.x;
    const int lane = tid & 63;
    const int w    = tid >> 6;
    const int lrow = lane & 15;
    const int quad = lane >> 4;
    const int bid  = blockIdx.x;
    const int grp  = bid >> 6;
    const int cb   = bid & 63;
    const int c0   = cb * 16;
    const int m0   = grp * 16;
    const int kbase = w * 256;
    int* gsl    = slots + grp * 256;
    int* myflag = gsl + (w << 6) + lane;   // 64 producer-wave flags (contig)
    int* self   = gsl + cb * 4 + w;        // own wave flag

    // ---- stage W slice into LDS (once). chunk c: row=c>>7, slot=c&127.
    // LDS 16B slot swizzle: slot' = slot ^ (row&15)
#pragma unroll
    for (int i = 0; i < 24; i++) {
        int c    = tid + 256 * i;
        int row  = c >> 7;
        int slot = c & 127;
        int g    = row >> 4;
        int r16  = row & 15;
        const short* src = Whh + ((long)(g * HID_ + c0 + r16)) * HID_ + slot * 8;
        *(s8v*)(Wlds + row * 1024 + ((slot ^ r16) << 3)) = *(const s8v*)src;
    }
    if (tid < 16) bnl[tid] = bhh[2 * HID_ + c0 + tid];

    // per-thread gate element: (mloc = tid>>4, j = tid&15); wave owns rows 4w..4w+4
    const int mloc = tid >> 4;
    const int j    = tid & 15;
    const int mg   = m0 + mloc;
    float hfp = 0.f;

    // zero own h0 slice in ring buf 0 (LLC-coherent u32 pairs)
    if (!(tid & 1)) {
        unsigned int* hp = (unsigned int*)(Hring + mg * HID_ + c0 + j);
        __hip_atomic_store(hp, 0u, __ATOMIC_RELAXED, __HIP_MEMORY_SCOPE_AGENT);
    }
    // prefetch x-proj for t=0
    const long tstride = (long)B_ * G3_;
    const short* xpb = XPt + (long)mg * G3_ + c0 + j;
    short xr_s = xpb[0], xz_s = xpb[HID_], xn_s = xpb[2 * HID_];

    // per-wave signal: h0 rows published (epoch 1)
    asm volatile("s_waitcnt vmcnt(0)" ::: "memory");
    if (lane == 0)
        __hip_atomic_store(self, 1, __ATOMIC_RELAXED, __HIP_MEMORY_SCOPE_AGENT);
    __syncthreads();   // W LDS + bnl ready

#pragma unroll 1
    for (int t = 0; t < T_; t++) {
        const short* Hc = Hring + ((long)(t & 3) << 16);
        short*       Hn = (short*)Hring + ((long)((t + 1) & 3) << 16);

        // per-wave poll: 64 producer-wave flags (one load/lane)
        while (true) {
            int v = __hip_atomic_load(myflag, __ATOMIC_RELAXED,
                                      __HIP_MEMORY_SCOPE_AGENT);
            if (__all(v >= t + 1)) break;
        }

        // batch-issue all 8 h fragments (LLC loads pipeline)
        bf8 a[8];
#pragma unroll
        for (int kk = 0; kk < 8; kk++)
            a[kk] = ldb8_llc(Hc + (m0 + lrow) * HID_ + kbase + kk * 32 + quad * 8);

        // issue next-step XP prefetch NOW (hidden under MFMA+reduce)
        int tn = (t + 1 < T_) ? t + 1 : t;
        const short* xp = xpb + (long)tn * tstride;
        short xr_n = xp[0], xz_n = xp[HID_], xn_n = xp[2 * HID_];

        f4 acc[3];
        const f4 zf = {0.f, 0.f, 0.f, 0.f};
        acc[0] = zf; acc[1] = zf; acc[2] = zf;

        // W from LDS (swizzled slots); 3 ds_read_b128 + 3 MFMA per kk
#pragma unroll
        for (int kk = 0; kk < 8; kk++) {
            int slotIdx = w * 32 + kk * 4 + quad;
            int swz = (slotIdx ^ lrow) << 3;
#pragma unroll
            for (int g = 0; g < 3; g++) {
                bf8 wf = ldb8(Wlds + (g * 16 + lrow) * 1024 + swz);
                acc[g] = __builtin_amdgcn_mfma_f32_16x16x32_bf16(
                    a[kk], wf, acc[g], 0, 0, 0);
            }
        }

        // wave partials -> LDS (slot t&1). m = quad*4 + r, col = g*16 + lrow
        float* rb = red[t & 1];
#pragma unroll
        for (int g = 0; g < 3; g++)
#pragma unroll
            for (int r = 0; r < 4; r++)
                rb[(w * 16 + quad * 4 + r) * 50 + g * 16 + lrow] = acc[g][r];
        __syncthreads();

        // cross-wave reduce + gates (1 element/thread)
        float ghr = 0.f, ghz = 0.f, ghn = 0.f;
#pragma unroll
        for (int ww = 0; ww < 4; ww++) {
            const float* rr = rb + (ww * 16 + mloc) * 50 + j;
            ghr += rr[0];
            ghz += rr[16];
            ghn += rr[32];
        }

        float rg = 1.f / (1.f + __expf(-(b2f(xr_s) + ghr)));   // biases folded
        float ug = 1.f / (1.f + __expf(-(b2f(xz_s) + ghz)));
        float xa = b2f(xn_s) + rg * (ghn + bnl[j]);
        float e  = __expf(-2.f * fabsf(xa));                   // fast tanh
        float ng = copysignf((1.f - e) / (1.f + e), xa);
        float hnew = (1.f - ug) * ng + ug * hfp;
        hfp = hnew;

        // h store (LLC u32 pair) + Out store, then per-wave drain + signal
        short hb = f2b(hnew);
        int prt = __shfl_xor((int)hb, 1);
        if (!(tid & 1)) {
            unsigned int pk = (unsigned int)(unsigned short)hb |
                              ((unsigned int)(unsigned short)prt << 16);
            unsigned int* hp = (unsigned int*)(Hn + mg * HID_ + c0 + j);
            __hip_atomic_store(hp, pk, __ATOMIC_RELAXED, __HIP_MEMORY_SCOPE_AGENT);
        }
        Out[((long)mg * T_ + t) * HID_ + c0 + j] = hnew;

        asm volatile("s_waitcnt vmcnt(0)" ::: "memory");
        if (lane == 0)
            __hip_atomic_store(self, t + 2, __ATOMIC_RELAXED,
                               __HIP_MEMORY_SCOPE_AGENT);

        xr_s = xr_n; xz_s = xz_n; xn_s = xn_n;
    }
}

extern "C" void kernel_launch(void* const* d_in, const int* in_sizes, int n_in,
                              void* d_out, int out_size, void* d_ws, size_t ws_size,
                              hipStream_t stream) {
    const float* Z   = (const float*)d_in[0];   // (64,512,512)
    const float* Wih = (const float*)d_in[1];   // (3072,512)
    const float* Whh = (const float*)d_in[2];   // (3072,1024)
    const float* bih = (const float*)d_in[3];   // (3072)
    const float* bhh = (const float*)d_in[4];   // (3072)
    float* out = (float*)d_out;                 // (64,512,1024) fp32

    char* ws = (char*)d_ws;
    size_t off = 0;
    short* XPt   = (short*)(ws + off); off += (size_t)B_ * T_ * G3_ * 2;   // 201.3 MB
    short* Wihbf = (short*)(ws + off); off += (size_t)G3_ * LAT_ * 2;      // 3.1 MB
    short* Whhbf = (short*)(ws + off); off += (size_t)G3_ * HID_ * 2;      // 6.3 MB
    short* Hring = (short*)(ws + off); off += (size_t)4 * B_ * HID_ * 2;   // 512 KB
    int*   slots = (int*)(ws + off);   off += 4 * 256 * 4;                 // 4 KB

    cvt_f2b_kernel<<<(G3_ * LAT_) / 1024, 256, 0, stream>>>(Wih, Wihbf, G3_ * LAT_);
    cvt_f2b_kernel<<<(G3_ * HID_) / 1024, 256, 0, stream>>>(Whh, Whhbf, G3_ * HID_);

    xproj_kernel<<<dim3(24, 256), 256, 0, stream>>>(Z, Wihbf, bih, bhh, XPt);

    init_slots<<<4, 256, 0, stream>>>(slots);

    // persistent recurrence: 256 blocks (4 batch-groups x 64 col-blocks),
    // one block per CU (LDS ~122 KB/block).
    gru_persist<<<256, 256, 0, stream>>>(Whhbf, XPt, bhh, Hring, out, slots);
}